// Round 1
// baseline (50.032 us; speedup 1.0000x reference)
//
#include <hip/hip_runtime.h>

#define BSZ 2048
#define DIM 256

// One block per graph. Block = 256 threads = 4 waves.
//   thread tid: rg = tid>>6 (row group 0..3), cg = tid&63 (column group, 4 floats)
// Phase 1: all threads cooperatively scan graph_len (2048 ints, L1-resident)
//          to get this block's segment start offset and the global max len.
// Phase 2: float4-vectorized segment sum, rows strided by 4 across row groups.
// Phase 3: LDS combine of the 4 row-group partials, scale by 1/max, store.
__global__ __launch_bounds__(256) void graph_mean_kernel(
    const float* __restrict__ emb,
    const int*   __restrict__ len,
    float*       __restrict__ out)
{
    const int b   = blockIdx.x;
    const int tid = threadIdx.x;

    __shared__ int s_off[256];
    __shared__ int s_max[256];

    // ---- Phase 1: offset (= sum len[0..b)) and global max(len) ----
    int po = 0, pm = 0;
    for (int i = tid; i < BSZ; i += 256) {
        int l = len[i];
        if (i < b) po += l;
        pm = max(pm, l);
    }
    s_off[tid] = po;
    s_max[tid] = pm;
    __syncthreads();
    #pragma unroll
    for (int s = 128; s > 0; s >>= 1) {
        if (tid < s) {
            s_off[tid] += s_off[tid + s];
            s_max[tid]  = max(s_max[tid], s_max[tid + s]);
        }
        __syncthreads();
    }
    const int   start   = s_off[0];
    const int   mylen   = len[b];
    const float inv_max = 1.0f / (float)s_max[0];
    __syncthreads();   // s_off/s_max no longer needed; s_part is separate anyway

    // ---- Phase 2: segment sum, float4 loads ----
    const int cg = tid & 63;   // columns cg*4 .. cg*4+3
    const int rg = tid >> 6;   // row group 0..3

    float4 acc = make_float4(0.f, 0.f, 0.f, 0.f);
    const float* base = emb + (size_t)start * DIM + (size_t)cg * 4;
    for (int r = rg; r < mylen; r += 4) {
        const float4 v = *reinterpret_cast<const float4*>(base + (size_t)r * DIM);
        acc.x += v.x; acc.y += v.y; acc.z += v.z; acc.w += v.w;
    }

    // ---- Phase 3: combine row groups in LDS, scale, store ----
    __shared__ float4 s_part[4][64];
    s_part[rg][cg] = acc;
    __syncthreads();

    if (rg == 0) {
        const float4 a0 = s_part[0][cg];
        const float4 a1 = s_part[1][cg];
        const float4 a2 = s_part[2][cg];
        const float4 a3 = s_part[3][cg];
        float4 r;
        r.x = (a0.x + a1.x + a2.x + a3.x) * inv_max;
        r.y = (a0.y + a1.y + a2.y + a3.y) * inv_max;
        r.z = (a0.z + a1.z + a2.z + a3.z) * inv_max;
        r.w = (a0.w + a1.w + a2.w + a3.w) * inv_max;
        *reinterpret_cast<float4*>(out + (size_t)b * DIM + (size_t)cg * 4) = r;
    }
}

extern "C" void kernel_launch(void* const* d_in, const int* in_sizes, int n_in,
                              void* d_out, int out_size, void* d_ws, size_t ws_size,
                              hipStream_t stream) {
    const float* emb = (const float*)d_in[0];
    const int*   len = (const int*)d_in[1];
    float*       out = (float*)d_out;

    graph_mean_kernel<<<BSZ, 256, 0, stream>>>(emb, len, out);
}